// Round 1
// baseline (283.191 us; speedup 1.0000x reference)
//
#include <hip/hip_runtime.h>

// Batched 8x8 DCT: out[n,u,v] = 0.25 * sum_{x,y} img[n,x,y]*alpha[x,y]*T[x,y,u,v] + 128
// Separable: out = M^T * img * M + 128, with M[i][j] = 0.5 * a[i] * C[i,j],
//   a[i]   = alpha[i,1]            (since a[1] == 1)
//   C[i,j] = dct_tensor[i,0,j,0]   (since cos((2v+1)*0) == 1)
// Memory-bound: 1 GB total traffic, floor ~170us at 6.3 TB/s.

#define WG 128          // threads per workgroup; one 8x8 block per thread
#define LDS_S 129       // transposed LDS stride (pad +1: conflict-free)

__global__ __launch_bounds__(WG, 2) void dct8x8_kernel(
    const float* __restrict__ image,
    const float* __restrict__ alpha,
    const float* __restrict__ dct,
    float* __restrict__ out,
    int nblocks)
{
    __shared__ float lds[64 * LDS_S];   // lds[k * LDS_S + local_block]
    const int t = threadIdx.x;
    const long long base_f = (long long)blockIdx.x * (WG * 64);   // first float of this WG
    const int total4 = nblocks * 16;                               // total float4 count
    const int base4 = blockIdx.x * (WG * 16);

    // ---- uniform M matrix (compiler keeps these as scalar/uniform loads) ----
    float M[8][8];
#pragma unroll
    for (int i = 0; i < 8; ++i) {
        const float ai = 0.5f * alpha[i * 8 + 1];
#pragma unroll
        for (int j = 0; j < 8; ++j)
            M[i][j] = ai * dct[i * 512 + j * 8];
    }

    // ---- coalesced global load -> transposed LDS ----
    const float4* in4 = (const float4*)(image + base_f);
#pragma unroll
    for (int i = 0; i < 16; ++i) {
        const int f4 = t + i * WG;              // 0..2047 within WG chunk
        if (base4 + f4 < total4) {
            const float4 v = in4[f4];
            const int b = f4 >> 4;              // local block 0..127
            const int k = (f4 & 15) * 4;        // element 0,4,...,60
            lds[(k + 0) * LDS_S + b] = v.x;
            lds[(k + 1) * LDS_S + b] = v.y;
            lds[(k + 2) * LDS_S + b] = v.z;
            lds[(k + 3) * LDS_S + b] = v.w;
        }
    }
    __syncthreads();

    // ---- stage 1: tmp[u][y] = sum_x M[x][u] * img[x][y] ----
    float tmp[8][8];
#pragma unroll
    for (int y = 0; y < 8; ++y) {
        float col[8];
#pragma unroll
        for (int x = 0; x < 8; ++x)
            col[x] = lds[(x * 8 + y) * LDS_S + t];   // stride-1 across lanes
#pragma unroll
        for (int u = 0; u < 8; ++u) {
            float acc = 0.0f;
#pragma unroll
            for (int x = 0; x < 8; ++x)
                acc = fmaf(M[x][u], col[x], acc);
            tmp[u][y] = acc;
        }
    }
    __syncthreads();   // all input reads done before overwriting lds

    // ---- stage 2: out[u][v] = sum_y tmp[u][y] * M[y][v] + 128 -> transposed LDS ----
#pragma unroll
    for (int u = 0; u < 8; ++u) {
#pragma unroll
        for (int v = 0; v < 8; ++v) {
            float acc = 128.0f;
#pragma unroll
            for (int y = 0; y < 8; ++y)
                acc = fmaf(tmp[u][y], M[y][v], acc);
            lds[(u * 8 + v) * LDS_S + t] = acc;
        }
    }
    __syncthreads();

    // ---- coalesced store from transposed LDS ----
    float4* out4 = (float4*)(out + base_f);
#pragma unroll
    for (int i = 0; i < 16; ++i) {
        const int f4 = t + i * WG;
        if (base4 + f4 < total4) {
            const int b = f4 >> 4;
            const int k = (f4 & 15) * 4;
            float4 v;
            v.x = lds[(k + 0) * LDS_S + b];
            v.y = lds[(k + 1) * LDS_S + b];
            v.z = lds[(k + 2) * LDS_S + b];
            v.w = lds[(k + 3) * LDS_S + b];
            out4[f4] = v;
        }
    }
}

extern "C" void kernel_launch(void* const* d_in, const int* in_sizes, int n_in,
                              void* d_out, int out_size, void* d_ws, size_t ws_size,
                              hipStream_t stream) {
    const float* image = (const float*)d_in[0];
    const float* alpha = (const float*)d_in[1];
    const float* dct   = (const float*)d_in[2];
    float* out = (float*)d_out;

    const int nblocks = in_sizes[0] / 64;          // number of 8x8 blocks
    const int grid = (nblocks + WG - 1) / WG;      // one 8x8 block per thread

    dct8x8_kernel<<<grid, WG, 0, stream>>>(image, alpha, dct, out, nblocks);
}